// Round 1
// baseline (432.528 us; speedup 1.0000x reference)
//
#include <hip/hip_runtime.h>

#define B 32
#define LC 512
#define LQ 64
#define DD 1024

// ws layout (floats):
// s1    [B*LQ]      @ 0
// mfull [B*LC]      @ 2048
// aq2c  [B*LC]      @ 18432
// q2c   [B*DD]      @ 34816
// sim   [B*LC*LQ]   @ 67584   (sim' = s1[j] + s2[i,j]; s0 folded into mfull only)

// ---------------- kernel 0: s1[b,j] = q[b,j,:] . proj_q ----------------
__global__ __launch_bounds__(256) void k0_s1(const float* __restrict__ q,
                                             const float* __restrict__ proj_q,
                                             float* __restrict__ s1) {
    int w = blockIdx.x * 4 + (threadIdx.x >> 6);   // 0..2047 = b*64+j
    int lane = threadIdx.x & 63;
    const float* qr = q + (size_t)w * DD;
    float acc = 0.f;
#pragma unroll
    for (int k = 0; k < 4; ++k) {
        int idx = k * 256 + lane * 4;
        float4 a = *(const float4*)(qr + idx);
        float4 p = *(const float4*)(proj_q + idx);
        acc += a.x * p.x + a.y * p.y + a.z * p.z + a.w * p.w;
    }
#pragma unroll
    for (int off = 32; off; off >>= 1) acc += __shfl_down(acc, off, 64);
    if (lane == 0) s1[w] = acc;
}

// ---------------- kernel 1: sim' tile GEMM + rowmax(m) + s0 ----------------
// block: 128 threads, tile 32 rows x 64 cols, K-chunks of 64
__global__ __launch_bounds__(128) void k1_sim(const float* __restrict__ c,
                                              const float* __restrict__ q,
                                              const float* __restrict__ proj_c,
                                              const float* __restrict__ proj_cq,
                                              const float* __restrict__ s1,
                                              float* __restrict__ sim,
                                              float* __restrict__ mfull) {
    const int b  = blockIdx.x >> 4;
    const int i0 = (blockIdx.x & 15) * 32;
    const int t  = threadIdx.x;

    __shared__ __align__(16) float cwT[64][36];   // [k][row], stride 144B (16B-mult)
    __shared__ __align__(16) float qT[64][68];    // [k][col], stride 272B
    __shared__ float s0red[32][4];
    __shared__ float s0f[32];

    const int tx = t & 15;        // col group: cols tx*4..+3
    const int ty = t >> 4;        // row group: rows ty*4..+3  (0..7)

    float acc[4][4] = {{0.f}};
    float s0p = 0.f;

    const int crow  = t >> 2;           // 0..31
    const int ckoff = (t & 3) * 16;
    const float* cbase = c + ((size_t)(b * LC + i0 + crow)) * DD + ckoff;
    const int qrow  = t >> 1;           // 0..63
    const int qkoff = (t & 1) * 32;
    const float* qbase = q + ((size_t)(b * LQ + qrow)) * DD + qkoff;

    for (int k0 = 0; k0 < DD; k0 += 64) {
        __syncthreads();
#pragma unroll
        for (int m = 0; m < 4; ++m) {
            float4 cv = *(const float4*)(cbase + k0 + 4 * m);
            float4 pq = *(const float4*)(proj_cq + k0 + ckoff + 4 * m);
            float4 pc = *(const float4*)(proj_c + k0 + ckoff + 4 * m);
            s0p += cv.x * pc.x + cv.y * pc.y + cv.z * pc.z + cv.w * pc.w;
            cwT[ckoff + 4 * m + 0][crow] = cv.x * pq.x;
            cwT[ckoff + 4 * m + 1][crow] = cv.y * pq.y;
            cwT[ckoff + 4 * m + 2][crow] = cv.z * pq.z;
            cwT[ckoff + 4 * m + 3][crow] = cv.w * pq.w;
        }
#pragma unroll
        for (int m = 0; m < 8; ++m) {
            float4 qv = *(const float4*)(qbase + k0 + 4 * m);
            qT[qkoff + 4 * m + 0][qrow] = qv.x;
            qT[qkoff + 4 * m + 1][qrow] = qv.y;
            qT[qkoff + 4 * m + 2][qrow] = qv.z;
            qT[qkoff + 4 * m + 3][qrow] = qv.w;
        }
        __syncthreads();
#pragma unroll 8
        for (int kk = 0; kk < 64; ++kk) {
            float4 a4 = *(const float4*)&cwT[kk][ty * 4];
            float4 b4 = *(const float4*)&qT[kk][tx * 4];
            acc[0][0] += a4.x * b4.x; acc[0][1] += a4.x * b4.y; acc[0][2] += a4.x * b4.z; acc[0][3] += a4.x * b4.w;
            acc[1][0] += a4.y * b4.x; acc[1][1] += a4.y * b4.y; acc[1][2] += a4.y * b4.z; acc[1][3] += a4.y * b4.w;
            acc[2][0] += a4.z * b4.x; acc[2][1] += a4.z * b4.y; acc[2][2] += a4.z * b4.z; acc[2][3] += a4.z * b4.w;
            acc[3][0] += a4.w * b4.x; acc[3][1] += a4.w * b4.y; acc[3][2] += a4.w * b4.z; acc[3][3] += a4.w * b4.w;
        }
    }

    // s0 per row: 4 partials per row -> reduce
    s0red[crow][t & 3] = s0p;
    __syncthreads();
    if (t < 32) s0f[t] = s0red[t][0] + s0red[t][1] + s0red[t][2] + s0red[t][3];
    __syncthreads();

    float4 s1v = *(const float4*)(s1 + b * LQ + tx * 4);
#pragma unroll
    for (int ii = 0; ii < 4; ++ii) {
        int r  = ty * 4 + ii;
        int ig = i0 + r;
        float v0 = acc[ii][0] + s1v.x;
        float v1 = acc[ii][1] + s1v.y;
        float v2 = acc[ii][2] + s1v.z;
        float v3 = acc[ii][3] + s1v.w;
        float rmax = fmaxf(fmaxf(v0, v1), fmaxf(v2, v3));
#pragma unroll
        for (int off = 1; off < 16; off <<= 1) rmax = fmaxf(rmax, __shfl_xor(rmax, off, 64));
        if (tx == 0) mfull[b * LC + ig] = rmax + s0f[r];
        float4 o = {v0, v1, v2, v3};
        *(float4*)(sim + ((size_t)(b * LC + ig)) * LQ + tx * 4) = o;
    }
}

// ---------------- kernel 2b: a_q2c[b,:] = softmax_i(mfull[b,:]) ----------------
__global__ __launch_bounds__(512) void k2b_aq2c(const float* __restrict__ mfull,
                                                float* __restrict__ aq2c) {
    int b = blockIdx.x;
    int t = threadIdx.x;   // 0..511 = i
    float v = mfull[b * LC + t];
    __shared__ float redm[8];
    __shared__ float reds[8];
    float mx = v;
#pragma unroll
    for (int off = 32; off; off >>= 1) mx = fmaxf(mx, __shfl_xor(mx, off, 64));
    if ((t & 63) == 0) redm[t >> 6] = mx;
    __syncthreads();
    float bm = redm[0];
#pragma unroll
    for (int i = 1; i < 8; ++i) bm = fmaxf(bm, redm[i]);
    float e = __expf(v - bm);
    float s = e;
#pragma unroll
    for (int off = 32; off; off >>= 1) s += __shfl_xor(s, off, 64);
    if ((t & 63) == 0) reds[t >> 6] = s;
    __syncthreads();
    float bs = 0.f;
#pragma unroll
    for (int i = 0; i < 8; ++i) bs += reds[i];
    aq2c[b * LC + t] = e / bs;
}

// ---------------- kernel 2c: q2c[b,d] = sum_i a[i] * c[b,i,d] ----------------
__global__ __launch_bounds__(256) void k2c_q2c(const float* __restrict__ c,
                                               const float* __restrict__ aq2c,
                                               float* __restrict__ q2c) {
    int b  = blockIdx.x >> 3;
    int d0 = (blockIdx.x & 7) * 128;
    int t  = threadIdx.x;
    __shared__ float aL[LC];
    for (int i = t; i < LC; i += 256) aL[i] = aq2c[b * LC + i];
    __syncthreads();
    int tx = t & 31, ty = t >> 5;   // ty: 0..7
    float4 acc = {0.f, 0.f, 0.f, 0.f};
    const float* cb = c + (size_t)b * LC * DD + d0 + tx * 4;
    for (int i = ty; i < LC; i += 8) {
        float a = aL[i];
        float4 cv = *(const float4*)(cb + (size_t)i * DD);
        acc.x += a * cv.x; acc.y += a * cv.y; acc.z += a * cv.z; acc.w += a * cv.w;
    }
    __shared__ __align__(16) float4 red[8][32];
    red[ty][tx] = acc;
    __syncthreads();
    if (t < 32) {
        float4 s = red[0][t];
#pragma unroll
        for (int k = 1; k < 8; ++k) {
            float4 v = red[k][t];
            s.x += v.x; s.y += v.y; s.z += v.z; s.w += v.w;
        }
        *(float4*)(q2c + b * DD + d0 + t * 4) = s;
    }
}

// ---------------- kernel 3: softmax rows, c2q = P*q, concat write ----------------
__global__ __launch_bounds__(256) void k3_out(const float* __restrict__ c,
                                              const float* __restrict__ q,
                                              const float* __restrict__ sim,
                                              const float* __restrict__ q2c,
                                              float* __restrict__ out) {
    int b  = blockIdx.x >> 4;
    int i0 = (blockIdx.x & 15) * 32;
    int t  = threadIdx.x;
    __shared__ __align__(16) float p[32][64];
    __shared__ __align__(16) float qc[64][128];

    int wave = t >> 6, lane = t & 63;
    for (int r = wave; r < 32; r += 4) {
        float v = sim[((size_t)(b * LC + i0 + r)) * LQ + lane];
        float mx = v;
#pragma unroll
        for (int off = 32; off; off >>= 1) mx = fmaxf(mx, __shfl_xor(mx, off, 64));
        float e = __expf(v - mx);
        float s = e;
#pragma unroll
        for (int off = 32; off; off >>= 1) s += __shfl_xor(s, off, 64);
        p[r][lane] = e / s;
    }

    int tx = t & 31;        // d-subtile: floats tx*4..+3 within 128-chunk
    int ty = t >> 5;        // 0..7: rows ty, ty+8, ty+16, ty+24 (and q-load row group)
    for (int d0 = 0; d0 < DD; d0 += 128) {
        __syncthreads();   // also guards p on first iteration
#pragma unroll
        for (int k = 0; k < 8; ++k) {
            int j = ty + 8 * k;
            *(float4*)&qc[j][tx * 4] = *(const float4*)(q + ((size_t)(b * LQ + j)) * DD + d0 + tx * 4);
        }
        __syncthreads();
        float4 acc[4] = {{0.f,0.f,0.f,0.f},{0.f,0.f,0.f,0.f},{0.f,0.f,0.f,0.f},{0.f,0.f,0.f,0.f}};
#pragma unroll 8
        for (int j = 0; j < 64; ++j) {
            float4 q4 = *(const float4*)&qc[j][tx * 4];
#pragma unroll
            for (int k = 0; k < 4; ++k) {
                float pv = p[ty + 8 * k][j];
                acc[k].x += pv * q4.x; acc[k].y += pv * q4.y;
                acc[k].z += pv * q4.z; acc[k].w += pv * q4.w;
            }
        }
        float4 g2 = *(const float4*)(q2c + b * DD + d0 + tx * 4);
#pragma unroll
        for (int k = 0; k < 4; ++k) {
            int i = i0 + ty + 8 * k;
            float4 cv = *(const float4*)(c + ((size_t)(b * LC + i)) * DD + d0 + tx * 4);
            float* ob = out + ((size_t)(b * LC + i)) * (4 * DD) + d0 + tx * 4;
            *(float4*)(ob) = cv;
            *(float4*)(ob + DD) = acc[k];
            float4 t2 = {cv.x * g2.x, cv.y * g2.y, cv.z * g2.z, cv.w * g2.w};
            *(float4*)(ob + 2 * DD) = t2;
            float4 t3 = {cv.x * acc[k].x, cv.y * acc[k].y, cv.z * acc[k].z, cv.w * acc[k].w};
            *(float4*)(ob + 3 * DD) = t3;
        }
    }
}

extern "C" void kernel_launch(void* const* d_in, const int* in_sizes, int n_in,
                              void* d_out, int out_size, void* d_ws, size_t ws_size,
                              hipStream_t stream) {
    const float* c       = (const float*)d_in[0];
    const float* q       = (const float*)d_in[1];
    const float* proj_c  = (const float*)d_in[2];
    const float* proj_q  = (const float*)d_in[3];
    const float* proj_cq = (const float*)d_in[4];
    float* out = (float*)d_out;
    float* ws  = (float*)d_ws;

    float* s1    = ws;
    float* mfull = ws + 2048;
    float* aq2c  = ws + 18432;
    float* q2c   = ws + 34816;
    float* sim   = ws + 67584;   // 1,048,576 floats

    hipLaunchKernelGGL(k0_s1,   dim3(512), dim3(256), 0, stream, q, proj_q, s1);
    hipLaunchKernelGGL(k1_sim,  dim3(512), dim3(128), 0, stream, c, q, proj_c, proj_cq, s1, sim, mfull);
    hipLaunchKernelGGL(k2b_aq2c,dim3(32),  dim3(512), 0, stream, mfull, aq2c);
    hipLaunchKernelGGL(k2c_q2c, dim3(256), dim3(256), 0, stream, c, aq2c, q2c);
    hipLaunchKernelGGL(k3_out,  dim3(512), dim3(256), 0, stream, c, q, sim, q2c, out);
}

// Round 2
// 390.637 us; speedup vs baseline: 1.1072x; 1.1072x over previous
//
#include <hip/hip_runtime.h>

#define B 32
#define LC 512
#define LQ 64
#define DD 1024

// ws layout (floats) — unchanged from round 1:
// s1    [B*LQ]      @ 0
// mfull [B*LC]      @ 2048
// aq2c  [B*LC]      @ 18432
// q2c   [B*DD]      @ 34816
// sim   [B*LC*LQ]   @ 67584

typedef __attribute__((ext_vector_type(8))) short bf16x8;   // 8 bf16 (4 VGPRs)
typedef __attribute__((ext_vector_type(4))) float f32x4;    // MFMA C/D

__device__ inline short f2bf(float f) {
    unsigned u = __builtin_bit_cast(unsigned, f);
    u += 0x7FFFu + ((u >> 16) & 1u);   // RNE
    return (short)(u >> 16);
}

__device__ inline bf16x8 pack8(float4 a, float4 b) {
    bf16x8 r;
    r[0] = f2bf(a.x); r[1] = f2bf(a.y); r[2] = f2bf(a.z); r[3] = f2bf(a.w);
    r[4] = f2bf(b.x); r[5] = f2bf(b.y); r[6] = f2bf(b.z); r[7] = f2bf(b.w);
    return r;
}

// ---------------- kernel 0: s1[b,j] = q[b,j,:] . proj_q ----------------
__global__ __launch_bounds__(256) void k0_s1(const float* __restrict__ q,
                                             const float* __restrict__ proj_q,
                                             float* __restrict__ s1) {
    int w = blockIdx.x * 4 + (threadIdx.x >> 6);   // 0..2047 = b*64+j
    int lane = threadIdx.x & 63;
    const float* qr = q + (size_t)w * DD;
    float acc = 0.f;
#pragma unroll
    for (int k = 0; k < 4; ++k) {
        int idx = k * 256 + lane * 4;
        float4 a = *(const float4*)(qr + idx);
        float4 p = *(const float4*)(proj_q + idx);
        acc += a.x * p.x + a.y * p.y + a.z * p.z + a.w * p.w;
    }
#pragma unroll
    for (int off = 32; off; off >>= 1) acc += __shfl_down(acc, off, 64);
    if (lane == 0) s1[w] = acc;
}

// ---------------- kernel 1: sim tile via bf16 MFMA + rowmax + s0 ----------------
// 512 blocks (2/CU), 256 threads = 4 waves. Block tile: M=32 rows x N=64 cols (full Lq).
// Wave w handles n-tile w*16..+15, both m-tiles. K chunks of 64.
__global__ __launch_bounds__(256) void k1_sim(const float* __restrict__ c,
                                              const float* __restrict__ q,
                                              const float* __restrict__ proj_c,
                                              const float* __restrict__ proj_cq,
                                              const float* __restrict__ s1,
                                              float* __restrict__ sim,
                                              float* __restrict__ mfull) {
    const int b  = blockIdx.x >> 4;
    const int i0 = (blockIdx.x & 15) * 32;
    const int t  = threadIdx.x;
    const int w  = t >> 6, lane = t & 63;
    const int l15 = lane & 15, quad = lane >> 4;

    __shared__ __align__(16) short sA[32][72];   // [row i][k], pad 72 (2-way on frag reads)
    __shared__ __align__(16) short sB[64][72];   // [row j][k]
    __shared__ float rmaxL[32][4];
    __shared__ float s0red[32][8];

    const int arow = t >> 3, ag = t & 7;    // A stage: row, d-off ag*8 (8 floats/thread)
    const int brow = t >> 2, bg = t & 3;    // B stage: row, d-off bg*16 (16 floats/thread)

    const float* cbase = c + (size_t)(b * LC + i0 + arow) * DD + ag * 8;
    const float* qbase = q + (size_t)(b * LQ + brow) * DD + bg * 16;

    f32x4 acc[2] = {{0.f,0.f,0.f,0.f},{0.f,0.f,0.f,0.f}};
    float s0p = 0.f;

    // prefetch chunk 0
    float4 a0 = *(const float4*)(cbase + 0);
    float4 a1 = *(const float4*)(cbase + 4);
    float4 b0 = *(const float4*)(qbase + 0);
    float4 b1 = *(const float4*)(qbase + 4);
    float4 b2 = *(const float4*)(qbase + 8);
    float4 b3 = *(const float4*)(qbase + 12);

    for (int kc = 0; kc < 16; ++kc) {
        float4 na0, na1, nb0, nb1, nb2, nb3;
        if (kc < 15) {
            const float* cn = cbase + (kc + 1) * 64;
            const float* qn = qbase + (kc + 1) * 64;
            na0 = *(const float4*)(cn + 0);
            na1 = *(const float4*)(cn + 4);
            nb0 = *(const float4*)(qn + 0);
            nb1 = *(const float4*)(qn + 4);
            nb2 = *(const float4*)(qn + 8);
            nb3 = *(const float4*)(qn + 12);
        }
        // convert + stage (uses current regs; proj vectors are L1/L2-hot)
        {
            const float* pcq = proj_cq + kc * 64 + ag * 8;
            const float* pc  = proj_c  + kc * 64 + ag * 8;
            float4 p0 = *(const float4*)(pcq + 0);
            float4 p1 = *(const float4*)(pcq + 4);
            float4 c0 = *(const float4*)(pc + 0);
            float4 c1 = *(const float4*)(pc + 4);
            s0p += a0.x * c0.x + a0.y * c0.y + a0.z * c0.z + a0.w * c0.w
                 + a1.x * c1.x + a1.y * c1.y + a1.z * c1.z + a1.w * c1.w;
            float4 m0 = {a0.x * p0.x, a0.y * p0.y, a0.z * p0.z, a0.w * p0.w};
            float4 m1 = {a1.x * p1.x, a1.y * p1.y, a1.z * p1.z, a1.w * p1.w};
            *(bf16x8*)&sA[arow][ag * 8] = pack8(m0, m1);
            *(bf16x8*)&sB[brow][bg * 16 + 0] = pack8(b0, b1);
            *(bf16x8*)&sB[brow][bg * 16 + 8] = pack8(b2, b3);
        }
        __syncthreads();
        // MFMA: 2 k-steps x (1 B-frag + 2 A-frags, 2 mfma)
#pragma unroll
        for (int s = 0; s < 2; ++s) {
            int ko = s * 32 + quad * 8;
            bf16x8 bf = *(const bf16x8*)&sB[w * 16 + l15][ko];
#pragma unroll
            for (int mt = 0; mt < 2; ++mt) {
                bf16x8 af = *(const bf16x8*)&sA[mt * 16 + l15][ko];
                acc[mt] = __builtin_amdgcn_mfma_f32_16x16x32_bf16(af, bf, acc[mt], 0, 0, 0);
            }
        }
        __syncthreads();
        if (kc < 15) { a0 = na0; a1 = na1; b0 = nb0; b1 = nb1; b2 = nb2; b3 = nb3; }
    }

    // epilogue: +s1, write sim, row-max, s0 -> mfull
    s0red[arow][ag] = s0p;
    float s1j = s1[b * LQ + w * 16 + l15];
#pragma unroll
    for (int mt = 0; mt < 2; ++mt) {
#pragma unroll
        for (int r = 0; r < 4; ++r) {
            float v = acc[mt][r] + s1j;
            int ig = i0 + mt * 16 + quad * 4 + r;
            sim[(size_t)(b * LC + ig) * LQ + w * 16 + l15] = v;
            float rm = v;
#pragma unroll
            for (int off = 1; off < 16; off <<= 1) rm = fmaxf(rm, __shfl_xor(rm, off, 16));
            if (l15 == 0) rmaxL[mt * 16 + quad * 4 + r][w] = rm;
        }
    }
    __syncthreads();
    if (t < 32) {
        float s0v = 0.f;
#pragma unroll
        for (int k = 0; k < 8; ++k) s0v += s0red[t][k];
        float mm = fmaxf(fmaxf(rmaxL[t][0], rmaxL[t][1]), fmaxf(rmaxL[t][2], rmaxL[t][3]));
        mfull[b * LC + i0 + t] = mm + s0v;
    }
}

// ---------------- kernel 2b: a_q2c[b,:] = softmax_i(mfull[b,:]) ----------------
__global__ __launch_bounds__(512) void k2b_aq2c(const float* __restrict__ mfull,
                                                float* __restrict__ aq2c) {
    int b = blockIdx.x;
    int t = threadIdx.x;
    float v = mfull[b * LC + t];
    __shared__ float redm[8];
    __shared__ float reds[8];
    float mx = v;
#pragma unroll
    for (int off = 32; off; off >>= 1) mx = fmaxf(mx, __shfl_xor(mx, off, 64));
    if ((t & 63) == 0) redm[t >> 6] = mx;
    __syncthreads();
    float bm = redm[0];
#pragma unroll
    for (int i = 1; i < 8; ++i) bm = fmaxf(bm, redm[i]);
    float e = __expf(v - bm);
    float s = e;
#pragma unroll
    for (int off = 32; off; off >>= 1) s += __shfl_xor(s, off, 64);
    if ((t & 63) == 0) reds[t >> 6] = s;
    __syncthreads();
    float bs = 0.f;
#pragma unroll
    for (int i = 0; i < 8; ++i) bs += reds[i];
    aq2c[b * LC + t] = e / bs;
}

// ---------------- kernel 2c: q2c[b,d] = sum_i a[i] * c[b,i,d] ----------------
__global__ __launch_bounds__(256) void k2c_q2c(const float* __restrict__ c,
                                               const float* __restrict__ aq2c,
                                               float* __restrict__ q2c) {
    int b  = blockIdx.x >> 3;
    int d0 = (blockIdx.x & 7) * 128;
    int t  = threadIdx.x;
    __shared__ float aL[LC];
    for (int i = t; i < LC; i += 256) aL[i] = aq2c[b * LC + i];
    __syncthreads();
    int tx = t & 31, ty = t >> 5;
    float4 acc = {0.f, 0.f, 0.f, 0.f};
    const float* cb = c + (size_t)b * LC * DD + d0 + tx * 4;
    for (int i = ty; i < LC; i += 8) {
        float a = aL[i];
        float4 cv = *(const float4*)(cb + (size_t)i * DD);
        acc.x += a * cv.x; acc.y += a * cv.y; acc.z += a * cv.z; acc.w += a * cv.w;
    }
    __shared__ __align__(16) float4 red[8][32];
    red[ty][tx] = acc;
    __syncthreads();
    if (t < 32) {
        float4 s = red[0][t];
#pragma unroll
        for (int k = 1; k < 8; ++k) {
            float4 v = red[k][t];
            s.x += v.x; s.y += v.y; s.z += v.z; s.w += v.w;
        }
        *(float4*)(q2c + b * DD + d0 + t * 4) = s;
    }
}

// ---------------- kernel 3: row softmax -> bf16 MFMA c2q -> concat write ----------------
// 512 blocks (2/CU), 256 threads = 4 waves. Block: 32 rows x D in chunks of 64.
__global__ __launch_bounds__(256) void k3_out(const float* __restrict__ c,
                                              const float* __restrict__ q,
                                              const float* __restrict__ sim,
                                              const float* __restrict__ q2c,
                                              float* __restrict__ out) {
    const int b  = blockIdx.x >> 4;
    const int i0 = (blockIdx.x & 15) * 32;
    const int t  = threadIdx.x;
    const int w  = t >> 6, lane = t & 63;
    const int l15 = lane & 15, quad = lane >> 4;

    __shared__ __align__(16) short pA[32][72];    // P, A-operand layout [i][j]
    __shared__ __align__(16) short sBq[64][72];   // q^T per chunk, [d][j]
    __shared__ __align__(16) float ct[32][68];    // c2q transpose buffer [i][d]

    // phase A: softmax of sim rows (wave w: rows w*8..w*8+7, lane = j)
#pragma unroll
    for (int rr = 0; rr < 8; ++rr) {
        int row = w * 8 + rr;
        float v = sim[(size_t)(b * LC + i0 + row) * LQ + lane];
        float mx = v;
#pragma unroll
        for (int off = 32; off; off >>= 1) mx = fmaxf(mx, __shfl_xor(mx, off, 64));
        float e = __expf(v - mx);
        float ss = e;
#pragma unroll
        for (int off = 32; off; off >>= 1) ss += __shfl_xor(ss, off, 64);
        pA[row][lane] = f2bf(e / ss);
    }

    const int j0 = (t & 31) * 2, dg = t >> 5;     // q staging: 2 j-rows, 8 d each
    const int erow = t >> 4, ed = (t & 15) * 4;   // epilogue: rows erow, erow+16; 4 d

    const float* qb0 = q + (size_t)(b * LQ + j0) * DD + dg * 8;
    const float* qb1 = qb0 + DD;

    // prefetch q chunk 0
    float4 r0 = *(const float4*)(qb0 + 0);
    float4 r1 = *(const float4*)(qb0 + 4);
    float4 r2 = *(const float4*)(qb1 + 0);
    float4 r3 = *(const float4*)(qb1 + 4);

    for (int dc = 0; dc < 16; ++dc) {
        const int d0 = dc * 64;
        float4 n0, n1, n2, n3;
        if (dc < 15) {
            n0 = *(const float4*)(qb0 + (dc + 1) * 64);
            n1 = *(const float4*)(qb0 + (dc + 1) * 64 + 4);
            n2 = *(const float4*)(qb1 + (dc + 1) * 64);
            n3 = *(const float4*)(qb1 + (dc + 1) * 64 + 4);
        }
        // epilogue global loads for this chunk (latency hidden behind MFMA phase)
        float4 cc0 = *(const float4*)(c + (size_t)(b * LC + i0 + erow) * DD + d0 + ed);
        float4 cc1 = *(const float4*)(c + (size_t)(b * LC + i0 + erow + 16) * DD + d0 + ed);
        float4 g2  = *(const float4*)(q2c + b * DD + d0 + ed);

        // stage q^T as bf16 pairs: sBq[d][j0], low=j0, high=j0+1
        const float* fr0 = (const float*)&r0;
        const float* fr1 = (const float*)&r1;
        const float* fr2 = (const float*)&r2;
        const float* fr3 = (const float*)&r3;
#pragma unroll
        for (int e = 0; e < 8; ++e) {
            float v0 = (e < 4) ? fr0[e] : fr1[e - 4];
            float v1 = (e < 4) ? fr2[e] : fr3[e - 4];
            unsigned pk = (unsigned)(unsigned short)f2bf(v0)
                        | ((unsigned)(unsigned short)f2bf(v1) << 16);
            *(unsigned*)&sBq[dg * 8 + e][j0] = pk;
        }
        __syncthreads();   // B1 (covers pA on first iteration)

        // MFMA: c2q[i][d] = sum_j P[i][j] q[j][d];  K = 64 (2 k-steps), fresh acc
        f32x4 acc[2] = {{0.f,0.f,0.f,0.f},{0.f,0.f,0.f,0.f}};
#pragma unroll
        for (int s = 0; s < 2; ++s) {
            int ko = s * 32 + quad * 8;
            bf16x8 bf = *(const bf16x8*)&sBq[w * 16 + l15][ko];
#pragma unroll
            for (int mt = 0; mt < 2; ++mt) {
                bf16x8 af = *(const bf16x8*)&pA[mt * 16 + l15][ko];
                acc[mt] = __builtin_amdgcn_mfma_f32_16x16x32_bf16(af, bf, acc[mt], 0, 0, 0);
            }
        }
        // scatter acc -> ct (transpose to row-major for coalesced writes)
#pragma unroll
        for (int mt = 0; mt < 2; ++mt)
#pragma unroll
            for (int r = 0; r < 4; ++r)
                ct[mt * 16 + quad * 4 + r][w * 16 + l15] = acc[mt][r];
        __syncthreads();   // B2

        // epilogue: 2 rows x 16B, 4 output segments, fully coalesced 256B/row-inst
#pragma unroll
        for (int k = 0; k < 2; ++k) {
            int row = erow + 16 * k;
            float4 cc = k ? cc1 : cc0;
            float4 cqv = *(const float4*)&ct[row][ed];
            float* ob = out + (size_t)(b * LC + i0 + row) * (4 * DD) + d0 + ed;
            *(float4*)(ob) = cc;
            *(float4*)(ob + DD) = cqv;
            float4 o2 = {cc.x * g2.x, cc.y * g2.y, cc.z * g2.z, cc.w * g2.w};
            *(float4*)(ob + 2 * DD) = o2;
            float4 o3 = {cc.x * cqv.x, cc.y * cqv.y, cc.z * cqv.z, cc.w * cqv.w};
            *(float4*)(ob + 3 * DD) = o3;
        }
        // no trailing barrier needed: next sBq writes are fenced by B2 of this
        // iteration (last sBq reads precede it); ct reads precede B1 of next.
        if (dc < 15) { r0 = n0; r1 = n1; r2 = n2; r3 = n3; }
    }
}

extern "C" void kernel_launch(void* const* d_in, const int* in_sizes, int n_in,
                              void* d_out, int out_size, void* d_ws, size_t ws_size,
                              hipStream_t stream) {
    const float* c       = (const float*)d_in[0];
    const float* q       = (const float*)d_in[1];
    const float* proj_c  = (const float*)d_in[2];
    const float* proj_q  = (const float*)d_in[3];
    const float* proj_cq = (const float*)d_in[4];
    float* out = (float*)d_out;
    float* ws  = (float*)d_ws;

    float* s1    = ws;
    float* mfull = ws + 2048;
    float* aq2c  = ws + 18432;
    float* q2c   = ws + 34816;
    float* sim   = ws + 67584;

    hipLaunchKernelGGL(k0_s1,    dim3(512), dim3(256), 0, stream, q, proj_q, s1);
    hipLaunchKernelGGL(k1_sim,   dim3(512), dim3(256), 0, stream, c, q, proj_c, proj_cq, s1, sim, mfull);
    hipLaunchKernelGGL(k2b_aq2c, dim3(32),  dim3(512), 0, stream, mfull, aq2c);
    hipLaunchKernelGGL(k2c_q2c,  dim3(256), dim3(256), 0, stream, c, aq2c, q2c);
    hipLaunchKernelGGL(k3_out,   dim3(512), dim3(256), 0, stream, c, q, sim, q2c, out);
}